// Round 2
// baseline (359.846 us; speedup 1.0000x reference)
//
#include <hip/hip_runtime.h>

// Superpixel max-pool: out[b][c][k] = max over pixels with spx[b,h,w]==k of img[b][c][h,w].
// Strategy: LDS privatization, exclusive output ownership (512 blocks = 8 batches x 64
// channel-pairs; each block owns out[b][c0:c0+2][:] -> no global atomics, no init pass).
//
// R1 lesson: bare ds_max_u32 atomics serialize at ~3.3 cyc/LANE in the CU's LDS unit
// (262k lane-atomics/CU -> 861k cyc -> 359 us). Fix: read-test-then-atomic. Plain
// ds_read_b32 is ~16x cheaper per lane; for random data only ~H(64)~=4.7 of 64
// candidates per (label,channel) actually improve the running max, so the atomic
// stream thins ~10x. Races only cause extra (correct) atomics - max is monotone.

#define NTHREADS 1024

constexpr int B_ = 8, C_ = 128, H_ = 256, W_ = 256, K_ = 1024;
constexpr int HW_ = H_ * W_;        // 65536
constexpr int CSUB = 2;             // channels per block
constexpr int CGRP = C_ / CSUB;     // 64 channel-groups per batch
constexpr int STRIDE = CSUB + 1;    // 3: odd -> label*3+c spreads LDS banks

// order-preserving float<->uint: monotone, so uint max == float max (bitwise exact)
__device__ __forceinline__ unsigned f2o(float f) {
    unsigned u = __float_as_uint(f);
    return u ^ (unsigned)(((int)u >> 31) | (int)0x80000000);
}
__device__ __forceinline__ float o2f(unsigned o) {
    return __uint_as_float(o ^ (((int)o >= 0) ? 0xFFFFFFFFu : 0x80000000u));
}

__global__ __launch_bounds__(NTHREADS) void SupPixPool_25366076850473_kernel(
    const float* __restrict__ img, const int* __restrict__ spx, float* __restrict__ out)
{
    __shared__ unsigned smax[K_ * STRIDE];   // 12 KB -> 2 blocks/CU, 32 waves/CU
    const int tid = threadIdx.x;

    // init to f2o(-inf) = 0x007FFFFF so empty segments produce -inf (segment_max semantics)
    for (int i = tid; i < K_ * STRIDE; i += NTHREADS)
        smax[i] = 0x007FFFFFu;
    __syncthreads();

    const int b  = blockIdx.x / CGRP;
    const int cg = blockIdx.x % CGRP;
    const int c0 = cg * CSUB;

    const int4*   lab4 = (const int4*)(spx + (size_t)b * HW_);
    const float4* img0 = (const float4*)(img + ((size_t)(b * C_ + c0)) * HW_);
    const float4* img1 = (const float4*)(img + ((size_t)(b * C_ + c0 + 1)) * HW_);
    constexpr int NV = HW_ / 4;              // 16384 vec4 groups, 16 iters/thread

    for (int v = tid; v < NV; v += NTHREADS) {
        int4 lab = lab4[v];                  // labels reused for both channels
        int a0 = lab.x * STRIDE, a1 = lab.y * STRIDE,
            a2 = lab.z * STRIDE, a3 = lab.w * STRIDE;
        float4 x0 = img0[v];
        float4 x1 = img1[v];
        unsigned o00 = f2o(x0.x), o01 = f2o(x0.y), o02 = f2o(x0.z), o03 = f2o(x0.w);
        unsigned o10 = f2o(x1.x), o11 = f2o(x1.y), o12 = f2o(x1.z), o13 = f2o(x1.w);
        // batch the 8 plain LDS reads so lgkmcnt waits pipeline
        unsigned c00 = smax[a0],     c01 = smax[a1],     c02 = smax[a2],     c03 = smax[a3];
        unsigned c10 = smax[a0 + 1], c11 = smax[a1 + 1], c12 = smax[a2 + 1], c13 = smax[a3 + 1];
        // exec-masked atomic commit only when strictly improving
        if (o00 > c00) atomicMax(&smax[a0],     o00);
        if (o01 > c01) atomicMax(&smax[a1],     o01);
        if (o02 > c02) atomicMax(&smax[a2],     o02);
        if (o03 > c03) atomicMax(&smax[a3],     o03);
        if (o10 > c10) atomicMax(&smax[a0 + 1], o10);
        if (o11 > c11) atomicMax(&smax[a1 + 1], o11);
        if (o12 > c12) atomicMax(&smax[a2 + 1], o12);
        if (o13 > c13) atomicMax(&smax[a3 + 1], o13);
    }
    __syncthreads();

    // exclusive epilogue: this block owns out[b][c0..c0+CSUB)[*]
    float* outb = out + ((size_t)(b * C_ + c0)) * K_;
    for (int i = tid; i < K_ * CSUB; i += NTHREADS) {
        int c = i >> 10;                     // K_ = 1024
        int k = i & (K_ - 1);
        outb[c * K_ + k] = o2f(smax[k * STRIDE + c]);
    }
}

extern "C" void kernel_launch(void* const* d_in, const int* in_sizes, int n_in,
                              void* d_out, int out_size, void* d_ws, size_t ws_size,
                              hipStream_t stream) {
    const float* img = (const float*)d_in[0];
    const int*   spx = (const int*)d_in[1];
    float*       out = (float*)d_out;        // fp32 output, [B][C][K]
    dim3 grid(B_ * CGRP);                    // 512 blocks
    hipLaunchKernelGGL(SupPixPool_25366076850473_kernel, grid, dim3(NTHREADS), 0, stream,
                       img, spx, out);
}